// Round 13
// baseline (382.567 us; speedup 1.0000x reference)
//
#include <hip/hip_runtime.h>
#include <hip/hip_bf16.h>

// h_out[v] = sum over edges (u->v) of features[u]
// NEW (needs ~105MB ws): two-key value-carrying sort -> no random READS.
//   n1: src-bucket hist (+pack features to bf16x5/16B, +zero hist2)
//   n2/n3: scans            n4: scatter (src_local<<17|dst) into src order
//   n5/n6: dst-hist per src-seg + slot bases
//   n7: per src-seg: gather from 6.3KB L1 window, scatter 12B value records
//   n8: per dst-bucket: stream records, LDS-accumulate, exclusive store
// MID (~30MB ws): R8 proven pipeline (~380us). LAST: direct atomics.

#define NN     100000
#define FD     5
#define NOUTT  (NN * FD)
#define BLK    256

// ---- new-path geometry ----
#define NSRCB  256
#define SRCW   391            // 256*391 = 100096 >= NN
#define NDSTB  256
#define DSTW   391
#define NCH    400            // pass-A chunk blocks (chunk = E/400)
#define DSTMSK 0x1FFFF        // dst fits 17 bits

typedef int vint4 __attribute__((ext_vector_type(4)));

__device__ __forceinline__ unsigned bf16rtn(float x) {
    unsigned u = __float_as_uint(x);
    u += 0x7fffu + ((u >> 16) & 1u);
    return u >> 16;
}
__device__ __forceinline__ float lo16(unsigned v) { return __uint_as_float(v << 16); }
__device__ __forceinline__ float hi16(unsigned v) { return __uint_as_float(v & 0xffff0000u); }

// ---------- n1: src hist (blocks<NCH) | feature pack | zero hist2 -----------
#define NPACKB ((NN + BLK - 1) / BLK)   // 391
#define NZB    64
__global__ __launch_bounds__(BLK) void n1_hist_pack(const int* __restrict__ src,
                                                    const float* __restrict__ f,
                                                    unsigned short* __restrict__ bh1,
                                                    uint4* __restrict__ fp,
                                                    int* __restrict__ hist2,
                                                    int chunk) {
    int bid = blockIdx.x;
    if (bid < NCH) {
        __shared__ int h[NSRCB];
        if (threadIdx.x < NSRCB) h[threadIdx.x] = 0;
        __syncthreads();
        long long e0 = (long long)bid * chunk;
        const vint4* s4 = (const vint4*)(src + e0);
        int n4 = chunk >> 2;
        for (int i = threadIdx.x; i < n4; i += BLK) {
            vint4 s = __builtin_nontemporal_load(&s4[i]);
            atomicAdd(&h[s[0] / SRCW], 1); atomicAdd(&h[s[1] / SRCW], 1);
            atomicAdd(&h[s[2] / SRCW], 1); atomicAdd(&h[s[3] / SRCW], 1);
        }
        __syncthreads();
        if (threadIdx.x < NSRCB)
            bh1[(size_t)bid * NSRCB + threadIdx.x] = (unsigned short)h[threadIdx.x];
    } else if (bid < NCH + NPACKB) {
        int i = (bid - NCH) * BLK + threadIdx.x;
        if (i < NN) {
            const float* r = f + (long long)i * FD;
            uint4 o;
            o.x = bf16rtn(r[0]) | (bf16rtn(r[1]) << 16);
            o.y = bf16rtn(r[2]) | (bf16rtn(r[3]) << 16);
            o.z = bf16rtn(r[4]);
            o.w = 0u;
            fp[i] = o;
        }
    } else {
        int base = (bid - NCH - NPACKB) * (NSRCB * NDSTB / NZB);
        for (int j = threadIdx.x; j < NSRCB * NDSTB / NZB; j += BLK)
            hist2[base + j] = 0;
    }
}

// ---------- n2: per src-bucket exclusive scan over NCH block counts ---------
__global__ __launch_bounds__(BLK) void n2_scan1(unsigned short* __restrict__ bh1,
                                                int* __restrict__ sbtot) {
    __shared__ int s[BLK];
    int b = blockIdx.x, t = threadIdx.x;
    int r0 = 2 * t, r1 = 2 * t + 1;
    int v0 = (r0 < NCH) ? (int)bh1[(size_t)r0 * NSRCB + b] : 0;
    int v1 = (r1 < NCH) ? (int)bh1[(size_t)r1 * NSRCB + b] : 0;
    int pair = v0 + v1;
    s[t] = pair;
    __syncthreads();
    for (int off = 1; off < BLK; off <<= 1) {
        int v = (t >= off) ? s[t - off] : 0;
        __syncthreads();
        s[t] += v;
        __syncthreads();
    }
    int base = s[t] - pair;
    if (r0 < NCH) bh1[(size_t)r0 * NSRCB + b] = (unsigned short)base;
    if (r1 < NCH) bh1[(size_t)r1 * NSRCB + b] = (unsigned short)(base + v0);
    if (t == BLK - 1) sbtot[b] = s[t];
}

// ---------- n3: exclusive scan of 256 src-bucket totals ---------------------
__global__ __launch_bounds__(BLK) void n3_base1(const int* __restrict__ sbtot,
                                                int* __restrict__ sbbase) {
    __shared__ int s[BLK];
    int t = threadIdx.x;
    int x = sbtot[t];
    s[t] = x;
    __syncthreads();
    for (int off = 1; off < BLK; off <<= 1) {
        int v = (t >= off) ? s[t - off] : 0;
        __syncthreads();
        s[t] += v;
        __syncthreads();
    }
    sbbase[t] = s[t] - x;
}

// ---------- n4: scatter packed (src_local<<17 | dst) into src order ---------
__global__ __launch_bounds__(BLK) void n4_scatter1(const int* __restrict__ src,
                                                   const int* __restrict__ dst,
                                                   const unsigned short* __restrict__ bh1,
                                                   const int* __restrict__ sbbase,
                                                   int* __restrict__ srt1, int chunk) {
    __shared__ int cur[NSRCB];
    int bid = blockIdx.x, t = threadIdx.x;
    if (t < NSRCB) cur[t] = sbbase[t] + (int)bh1[(size_t)bid * NSRCB + t];
    __syncthreads();
    long long e0 = (long long)bid * chunk;
    const vint4* s4 = (const vint4*)(src + e0);
    const vint4* d4 = (const vint4*)(dst + e0);
    int n4 = chunk >> 2;
    int i = t;
    for (; i + 3 * BLK < n4; i += 4 * BLK) {
        vint4 sv[4], dv[4];
#pragma unroll
        for (int k = 0; k < 4; ++k) {
            sv[k] = __builtin_nontemporal_load(&s4[i + k * BLK]);
            dv[k] = __builtin_nontemporal_load(&d4[i + k * BLK]);
        }
        __builtin_amdgcn_sched_barrier(0);
#pragma unroll
        for (int k = 0; k < 4; ++k) {
#pragma unroll
            for (int j = 0; j < 4; ++j) {
                int u = sv[k][j], v = dv[k][j];
                int sb = u / SRCW;
                int off = atomicAdd(&cur[sb], 1);
                srt1[off] = ((u - sb * SRCW) << 17) | v;
            }
        }
    }
    for (; i < n4; i += BLK) {
        vint4 sv = __builtin_nontemporal_load(&s4[i]);
        vint4 dv = __builtin_nontemporal_load(&d4[i]);
#pragma unroll
        for (int j = 0; j < 4; ++j) {
            int u = sv[j], v = dv[j];
            int sb = u / SRCW;
            int off = atomicAdd(&cur[sb], 1);
            srt1[off] = ((u - sb * SRCW) << 17) | v;
        }
    }
}

// ---------- n5: per src-segment dst-bucket histogram (2 blocks/segment) -----
__global__ __launch_bounds__(BLK) void n5_hist2(const int* __restrict__ srt1,
                                                const int* __restrict__ sbbase,
                                                const int* __restrict__ sbtot,
                                                int* __restrict__ hist2) {
    __shared__ int h[NDSTB];
    int s = blockIdx.x >> 1, half = blockIdx.x & 1, t = threadIdx.x;
    if (t < NDSTB) h[t] = 0;
    __syncthreads();
    int cnt = sbtot[s];
    int c0 = cnt >> 1;
    int start = sbbase[s] + (half ? c0 : 0);
    int num = half ? (cnt - c0) : c0;
    for (int i = t; i < num; i += BLK) {
        int w = srt1[start + i];
        atomicAdd(&h[(w & DSTMSK) / DSTW], 1);
    }
    __syncthreads();
    if (t < NDSTB && h[t] > 0) atomicAdd(&hist2[s * NDSTB + t], h[t]);
}

// ---------- n6: slot bases: srt2 = [dst-bucket][src-segment runs] -----------
__global__ __launch_bounds__(BLK) void n6_base2(const int* __restrict__ hist2,
                                                int* __restrict__ base2,
                                                int* __restrict__ dbase,
                                                int* __restrict__ dcnt) {
    __shared__ int s[BLK];
    int d = threadIdx.x;
    int tot = 0;
    for (int ss = 0; ss < NSRCB; ++ss) tot += hist2[ss * NDSTB + d];
    dcnt[d] = tot;
    s[d] = tot;
    __syncthreads();
    for (int off = 1; off < BLK; off <<= 1) {
        int v = (d >= off) ? s[d - off] : 0;
        __syncthreads();
        s[d] += v;
        __syncthreads();
    }
    int run = s[d] - tot;
    dbase[d] = run;
    for (int ss = 0; ss < NSRCB; ++ss) {
        base2[ss * NDSTB + d] = run;
        run += hist2[ss * NDSTB + d];
    }
}

// ---------- n7: L1-window gather + value-carrying 12B scatter ---------------
__global__ __launch_bounds__(BLK) void n7_scatter2(const int* __restrict__ srt1,
                                                   const uint4* __restrict__ fp,
                                                   const int* __restrict__ sbbase,
                                                   const int* __restrict__ sbtot,
                                                   const int* __restrict__ base2,
                                                   int* __restrict__ srt2) {
    __shared__ int cur[NDSTB];
    int s = blockIdx.x, t = threadIdx.x;
    if (t < NDSTB) cur[t] = base2[s * NDSTB + t];
    __syncthreads();
    int base = sbbase[s];
    int cnt = sbtot[s];
    int u0 = s * SRCW;
    int i = t;
    for (; i + 3 * BLK < cnt; i += 4 * BLK) {
        int w[4];
        uint4 g[4];
#pragma unroll
        for (int k = 0; k < 4; ++k) w[k] = srt1[base + i + k * BLK];
#pragma unroll
        for (int k = 0; k < 4; ++k) g[k] = fp[u0 + ((unsigned)w[k] >> 17)];
        __builtin_amdgcn_sched_barrier(0);
#pragma unroll
        for (int k = 0; k < 4; ++k) {
            int v = w[k] & DSTMSK;
            int d = v / DSTW;
            int dl = v - d * DSTW;
            int slot = atomicAdd(&cur[d], 1);
            int* p = srt2 + (size_t)slot * 3;
            p[0] = (int)g[k].x;
            p[1] = (int)g[k].y;
            p[2] = (int)((g[k].z & 0xFFFFu) | ((unsigned)dl << 16));
        }
    }
    for (; i < cnt; i += BLK) {
        int w = srt1[base + i];
        uint4 g = fp[u0 + ((unsigned)w >> 17)];
        int v = w & DSTMSK;
        int d = v / DSTW;
        int dl = v - d * DSTW;
        int slot = atomicAdd(&cur[d], 1);
        int* p = srt2 + (size_t)slot * 3;
        p[0] = (int)g.x;
        p[1] = (int)g.y;
        p[2] = (int)((g.z & 0xFFFFu) | ((unsigned)dl << 16));
    }
}

// ---------- n8: stream dst-bucket records, LDS-accumulate, store ------------
__global__ __launch_bounds__(BLK) void n8_reduce(const int* __restrict__ srt2,
                                                 const int* __restrict__ dbase,
                                                 const int* __restrict__ dcnt,
                                                 float* __restrict__ out) {
    __shared__ float acc[DSTW * FD];   // 7820 B
    int d = blockIdx.x, t = threadIdx.x;
    for (int j = t; j < DSTW * FD; j += BLK) acc[j] = 0.f;
    __syncthreads();
    int base = dbase[d];
    int n = dcnt[d];
    int i = t;
    for (; i + 3 * BLK < n; i += 4 * BLK) {
        int r[4][3];
#pragma unroll
        for (int k = 0; k < 4; ++k) {
            const int* p = srt2 + (size_t)(base + i + k * BLK) * 3;
            r[k][0] = p[0]; r[k][1] = p[1]; r[k][2] = p[2];
        }
        __builtin_amdgcn_sched_barrier(0);
#pragma unroll
        for (int k = 0; k < 4; ++k) {
            int dl = (unsigned)r[k][2] >> 16;
            float* p = acc + dl * FD;
            atomicAdd(&p[0], lo16((unsigned)r[k][0]));
            atomicAdd(&p[1], hi16((unsigned)r[k][0]));
            atomicAdd(&p[2], lo16((unsigned)r[k][1]));
            atomicAdd(&p[3], hi16((unsigned)r[k][1]));
            atomicAdd(&p[4], lo16((unsigned)r[k][2]));
        }
    }
    for (; i < n; i += BLK) {
        const int* p = srt2 + (size_t)(base + i) * 3;
        int r0 = p[0], r1 = p[1], r2 = p[2];
        int dl = (unsigned)r2 >> 16;
        float* a = acc + dl * FD;
        atomicAdd(&a[0], lo16((unsigned)r0)); atomicAdd(&a[1], hi16((unsigned)r0));
        atomicAdd(&a[2], lo16((unsigned)r1)); atomicAdd(&a[3], hi16((unsigned)r1));
        atomicAdd(&a[4], lo16((unsigned)r2));
    }
    __syncthreads();
    int node0 = d * DSTW;
    int nn = NN - node0; if (nn > DSTW) nn = DSTW;
    int nfl = nn * FD;
    float* o = out + (long long)node0 * FD;
    for (int j = t; j < nfl; j += BLK) o[j] = acc[j];
}

// ================= MID TIER: R8 proven pipeline (~30MB ws) ==================
#define M_NPS 32
#define M_SH  5
#define M_NB  3125
#define M_NSB 512
__global__ __launch_bounds__(BLK) void m2_hist(const int* __restrict__ dst,
                                               unsigned short* __restrict__ bh, int chunk) {
    __shared__ int h[M_NB];
    for (int b = threadIdx.x; b < M_NB; b += BLK) h[b] = 0;
    __syncthreads();
    long long e0 = (long long)blockIdx.x * chunk;
    const vint4* d4 = (const vint4*)(dst + e0);
    int n4 = chunk >> 2;
    for (int i = threadIdx.x; i < n4; i += BLK) {
        vint4 d = __builtin_nontemporal_load(&d4[i]);
        atomicAdd(&h[d[0] >> M_SH], 1); atomicAdd(&h[d[1] >> M_SH], 1);
        atomicAdd(&h[d[2] >> M_SH], 1); atomicAdd(&h[d[3] >> M_SH], 1);
    }
    __syncthreads();
    unsigned short* row = bh + (size_t)blockIdx.x * M_NB;
    for (int b = threadIdx.x; b < M_NB; b += BLK) row[b] = (unsigned short)h[b];
}
__global__ __launch_bounds__(BLK) void m3_scan(unsigned short* __restrict__ bh,
                                               int* __restrict__ btot) {
    __shared__ int s[BLK];
    int b = blockIdx.x, t = threadIdx.x;
    int v0 = bh[(size_t)(2 * t) * M_NB + b];
    int v1 = bh[(size_t)(2 * t + 1) * M_NB + b];
    int pair = v0 + v1;
    s[t] = pair;
    __syncthreads();
    for (int off = 1; off < BLK; off <<= 1) {
        int v = (t >= off) ? s[t - off] : 0;
        __syncthreads(); s[t] += v; __syncthreads();
    }
    int base = s[t] - pair;
    bh[(size_t)(2 * t) * M_NB + b] = (unsigned short)base;
    bh[(size_t)(2 * t + 1) * M_NB + b] = (unsigned short)(base + v0);
    if (t == BLK - 1) btot[b] = s[t];
}
#define M_VPT 13
__global__ __launch_bounds__(BLK) void m4_base(const int* __restrict__ btot,
                                               int* __restrict__ bbase) {
    __shared__ int s[BLK];
    int t = threadIdx.x;
    int v[M_VPT], sum = 0;
#pragma unroll
    for (int k = 0; k < M_VPT; ++k) {
        int i = M_VPT * t + k;
        v[k] = (i < M_NB) ? btot[i] : 0;
        sum += v[k];
    }
    s[t] = sum;
    __syncthreads();
    for (int off = 1; off < BLK; off <<= 1) {
        int u = (t >= off) ? s[t - off] : 0;
        __syncthreads(); s[t] += u; __syncthreads();
    }
    int run = s[t] - sum;
#pragma unroll
    for (int k = 0; k < M_VPT; ++k) {
        int i = M_VPT * t + k;
        if (i < M_NB) bbase[i] = run;
        run += v[k];
    }
}
__global__ __launch_bounds__(BLK) void m5_scatter(const int* __restrict__ src,
                                                  const int* __restrict__ dst,
                                                  const unsigned short* __restrict__ bh,
                                                  const int* __restrict__ bbase,
                                                  int* __restrict__ bdata, int chunk) {
    __shared__ int cur[M_NB];
    int blk = blockIdx.x;
    const unsigned short* row = bh + (size_t)blk * M_NB;
    for (int b = threadIdx.x; b < M_NB; b += BLK) cur[b] = bbase[b] + (int)row[b];
    __syncthreads();
    long long e0 = (long long)blk * chunk;
    const vint4* d4 = (const vint4*)(dst + e0);
    const vint4* s4 = (const vint4*)(src + e0);
    int n4 = chunk >> 2;
    for (int i = threadIdx.x; i < n4; i += BLK) {
        vint4 d = __builtin_nontemporal_load(&d4[i]);
        vint4 s = __builtin_nontemporal_load(&s4[i]);
#pragma unroll
        for (int j = 0; j < 4; ++j) {
            int vv = d[j], uu = s[j];
            int b = vv >> M_SH;
            int off = atomicAdd(&cur[b], 1);
            bdata[off] = (uu << M_SH) | (vv & (M_NPS - 1));
        }
    }
}
__global__ __launch_bounds__(BLK) void m1_pad(const float* __restrict__ f,
                                              uint4* __restrict__ fp) {
    int i = blockIdx.x * BLK + threadIdx.x;
    if (i < NN) {
        const float* r = f + (long long)i * FD;
        uint4 o;
        o.x = bf16rtn(r[0]) | (bf16rtn(r[1]) << 16);
        o.y = bf16rtn(r[2]) | (bf16rtn(r[3]) << 16);
        o.z = bf16rtn(r[4]);
        o.w = 0u;
        fp[i] = o;
    }
}
__global__ __launch_bounds__(BLK) void m6_gather(const int* __restrict__ bdata,
                                                 const uint4* __restrict__ fp,
                                                 const int* __restrict__ bbase,
                                                 const int* __restrict__ btot,
                                                 float* __restrict__ out) {
    __shared__ float acc[M_NPS * FD];
    int t = threadIdx.x;
    if (t < M_NPS * FD) acc[t] = 0.f;
    __syncthreads();
    int b = blockIdx.x;
    int base = bbase[b];
    int n = btot[b];
    int i = t;
    for (; i + 3 * BLK < n; i += 4 * BLK) {
        int l[4]; uint4 g[4];
#pragma unroll
        for (int k = 0; k < 4; ++k) {
            int w = bdata[base + i + k * BLK];
            l[k] = w & (M_NPS - 1);
            g[k] = fp[w >> M_SH];
        }
        __builtin_amdgcn_sched_barrier(0);
#pragma unroll
        for (int k = 0; k < 4; ++k) {
            float* p = acc + l[k] * FD;
            atomicAdd(&p[0], lo16(g[k].x)); atomicAdd(&p[1], hi16(g[k].x));
            atomicAdd(&p[2], lo16(g[k].y)); atomicAdd(&p[3], hi16(g[k].y));
            atomicAdd(&p[4], lo16(g[k].z));
        }
    }
    for (; i < n; i += BLK) {
        int w = bdata[base + i];
        int l = w & (M_NPS - 1);
        uint4 g = fp[w >> M_SH];
        float* p = acc + l * FD;
        atomicAdd(&p[0], lo16(g.x)); atomicAdd(&p[1], hi16(g.x));
        atomicAdd(&p[2], lo16(g.y)); atomicAdd(&p[3], hi16(g.y));
        atomicAdd(&p[4], lo16(g.z));
    }
    __syncthreads();
    if (t < M_NPS * FD) out[(size_t)b * M_NPS * FD + t] = acc[t];
}

// ---------- last-resort fallback --------------------------------------------
__global__ void scatter_add_fallback(const float* __restrict__ features,
                                     const int* __restrict__ src,
                                     const int* __restrict__ dst,
                                     float* __restrict__ out, int n_edges) {
    int idx = blockIdx.x * blockDim.x + threadIdx.x;
    int stride = gridDim.x * blockDim.x;
    for (int e = idx; e < n_edges; e += stride) {
        int u = src[e], v = dst[e];
        const float* f = features + (long long)u * FD;
        float* o = out + (long long)v * FD;
#pragma unroll
        for (int k = 0; k < FD; ++k) atomicAdd(&o[k], f[k]);
    }
}

static inline size_t al16(size_t x) { return (x + 15) & ~(size_t)15; }

extern "C" void kernel_launch(void* const* d_in, const int* in_sizes, int n_in,
                              void* d_out, int out_size, void* d_ws, size_t ws_size,
                              hipStream_t stream) {
    const float* features = (const float*)d_in[0];
    const int*   src      = (const int*)d_in[1];
    const int*   dst      = (const int*)d_in[2];
    float* out = (float*)d_out;
    int n_edges = in_sizes[1];
    char* w = (char*)d_ws;

    // ---- new-path carve (~105MB) ----
    size_t o_s1 = 0;
    size_t o_s2 = al16(o_s1 + (size_t)n_edges * 4);
    size_t o_fp = al16(o_s2 + (size_t)n_edges * 12);
    size_t o_b1 = al16(o_fp + (size_t)NN * 16);
    size_t o_st = al16(o_b1 + (size_t)NCH * NSRCB * 2);
    size_t o_sb = al16(o_st + NSRCB * 4);
    size_t o_h2 = al16(o_sb + NSRCB * 4);
    size_t o_b2 = al16(o_h2 + (size_t)NSRCB * NDSTB * 4);
    size_t o_db = al16(o_b2 + (size_t)NSRCB * NDSTB * 4);
    size_t o_dc = al16(o_db + NDSTB * 4);
    size_t needN = o_dc + NDSTB * 4;

    bool okN = (out_size == NOUTT) && (in_sizes[0] == NOUTT) &&
               (n_edges % (NCH * 4) == 0) && (needN <= ws_size);

    if (okN) {
        int*            srt1  = (int*)(w + o_s1);
        int*            srt2  = (int*)(w + o_s2);
        uint4*          fpad  = (uint4*)(w + o_fp);
        unsigned short* bh1   = (unsigned short*)(w + o_b1);
        int*            sbtot = (int*)(w + o_st);
        int*            sbbase= (int*)(w + o_sb);
        int*            hist2 = (int*)(w + o_h2);
        int*            base2 = (int*)(w + o_b2);
        int*            dbase = (int*)(w + o_db);
        int*            dcnt  = (int*)(w + o_dc);
        int chunk = n_edges / NCH;
        n1_hist_pack<<<NCH + NPACKB + NZB, BLK, 0, stream>>>(src, features, bh1,
                                                             fpad, hist2, chunk);
        n2_scan1   <<<NSRCB, BLK, 0, stream>>>(bh1, sbtot);
        n3_base1   <<<1, BLK, 0, stream>>>(sbtot, sbbase);
        n4_scatter1<<<NCH, BLK, 0, stream>>>(src, dst, bh1, sbbase, srt1, chunk);
        n5_hist2   <<<2 * NSRCB, BLK, 0, stream>>>(srt1, sbbase, sbtot, hist2);
        n6_base2   <<<1, BLK, 0, stream>>>(hist2, base2, dbase, dcnt);
        n7_scatter2<<<NSRCB, BLK, 0, stream>>>(srt1, fpad, sbbase, sbtot, base2, srt2);
        n8_reduce  <<<NDSTB, BLK, 0, stream>>>(srt2, dbase, dcnt, out);
        return;
    }

    // ---- mid-tier carve (R8, ~30MB) ----
    size_t mo_bd = 0;
    size_t mo_r1 = al16(mo_bd + (size_t)n_edges * 4 + 32);
    size_t sz_r1 = (size_t)M_NSB * M_NB * 2;
    size_t sz_fp = (size_t)NN * 16;
    if (sz_fp > sz_r1) sz_r1 = sz_fp;
    size_t mo_bb = al16(mo_r1 + sz_r1);
    size_t mo_bt = mo_bb + (size_t)M_NB * 4;
    size_t needM = mo_bt + (size_t)M_NB * 4;
    bool okM = (out_size == NOUTT) && (in_sizes[0] == NOUTT) &&
               (n_edges % (M_NSB * 4) == 0) && (needM <= ws_size);
    if (okM) {
        int*            bdata = (int*)(w + mo_bd);
        unsigned short* bhist = (unsigned short*)(w + mo_r1);
        uint4*          fpad  = (uint4*)(w + mo_r1);
        int*            bbase = (int*)(w + mo_bb);
        int*            btot  = (int*)(w + mo_bt);
        int chunk = n_edges / M_NSB;
        m2_hist   <<<M_NSB, BLK, 0, stream>>>(dst, bhist, chunk);
        m3_scan   <<<M_NB, BLK, 0, stream>>>(bhist, btot);
        m4_base   <<<1, BLK, 0, stream>>>(btot, bbase);
        m5_scatter<<<M_NSB, BLK, 0, stream>>>(src, dst, bhist, bbase, bdata, chunk);
        m1_pad    <<<(NN + BLK - 1) / BLK, BLK, 0, stream>>>(features, fpad);
        m6_gather <<<M_NB, BLK, 0, stream>>>(bdata, fpad, bbase, btot, out);
        return;
    }

    (void)hipMemsetAsync(d_out, 0, (size_t)out_size * sizeof(float), stream);
    int grid = (n_edges + BLK - 1) / BLK;
    if (grid > 65535) grid = 65535;
    scatter_add_fallback<<<grid, BLK, 0, stream>>>(features, src, dst, out, n_edges);
}